// Round 4
// baseline (3292.037 us; speedup 1.0000x reference)
//
#include <hip/hip_runtime.h>
#include <hip/hip_fp16.h>
#include <hip/hip_cooperative_groups.h>

#define B_  16
#define TA  2048
#define TV  1024
#define DD  512
#define NIT 20

static constexpr float EPSI  = 0.15f;
static constexpr float LOG2E = 1.4426950408889634f;

using f32x4 = __attribute__((ext_vector_type(4))) float;
using half8 = __attribute__((ext_vector_type(8))) _Float16;
using half4 = __attribute__((ext_vector_type(4))) _Float16;

__device__ inline float wave_sum(float x) {
  #pragma unroll
  for (int m = 32; m; m >>= 1) x += __shfl_xor(x, m, 64);
  return x;
}

// ---------------- norms: inv L2 norm per row (audio rows then video rows) ---
__global__ __launch_bounds__(256) void norms_k(const float* __restrict__ audio,
                                               const float* __restrict__ video,
                                               float* __restrict__ inv_na,
                                               float* __restrict__ inv_nv) {
  int wid  = (blockIdx.x * blockDim.x + threadIdx.x) >> 6;
  int lane = threadIdx.x & 63;
  const float* src;
  float* dst;
  if (wid < B_ * TA) { src = audio + (size_t)wid * DD; dst = inv_na + wid; }
  else               { src = video + (size_t)(wid - B_ * TA) * DD; dst = inv_nv + (wid - B_ * TA); }
  const float4* s4 = (const float4*)src;
  float ss = 0.f;
  #pragma unroll
  for (int i = 0; i < 2; i++) {
    float4 v = s4[lane + i * 64];
    ss += v.x * v.x + v.y * v.y + v.z * v.z + v.w * v.w;
  }
  ss = wave_sum(ss);
  if (lane == 0) *dst = 1.0f / fmaxf(sqrtf(ss), 1e-12f);
}

// ---------------- v' init: v' = -c1 * lam_q * (1 - quality) ----------------
__global__ void vinit_k(const float* __restrict__ quality,
                        const float* __restrict__ lam_q,
                        float* __restrict__ Vp) {
  int i = blockIdx.x * blockDim.x + threadIdx.x;  // 0..B_*TV-1
  float c1 = LOG2E / EPSI;
  Vp[i] = -c1 * (*lam_q) * (1.0f - quality[i]);
}

// ---------------- cost GEMM: Ksmall2 = c1*(sim - 1 - lt*timedist) ----------
#define BM 128
#define BN 128
#define BK 64
#define LDH 72

template<bool F16>
__global__ __launch_bounds__(256) void cost_k(const float* __restrict__ audio,
                                              const float* __restrict__ video,
                                              const float* __restrict__ inv_na,
                                              const float* __restrict__ inv_nv,
                                              const float* __restrict__ lam_t,
                                              float* __restrict__ Kb,
                                              _Float16* __restrict__ Kh) {
  __shared__ _Float16 As[BM * LDH];
  __shared__ _Float16 Bs[BN * LDH];
  int b  = blockIdx.z;
  int a0 = blockIdx.x * BM;
  int j0 = blockIdx.y * BN;
  int tid  = threadIdx.x;
  int lane = tid & 63;
  int wid  = tid >> 6;
  int wm = wid >> 1, wn = wid & 1;

  const float* Ab = audio + (size_t)b * TA * DD;
  const float* Vb = video + (size_t)b * TV * DD;

  f32x4 acc[4][4];
  #pragma unroll
  for (int i = 0; i < 4; i++)
    #pragma unroll
    for (int j = 0; j < 4; j++)
      #pragma unroll
      for (int r = 0; r < 4; r++) acc[i][j][r] = 0.f;

  int frow = tid >> 4;
  int fcol = (tid & 15) * 4;
  int l16 = lane & 15, lq = lane >> 4;

  for (int kb = 0; kb < DD; kb += BK) {
    __syncthreads();
    #pragma unroll
    for (int s = 0; s < 8; s++) {
      int r = frow + s * 16;
      float4 v = *(const float4*)&Ab[(size_t)(a0 + r) * DD + kb + fcol];
      float sc = inv_na[b * TA + a0 + r];
      half4 h = { (_Float16)(v.x * sc), (_Float16)(v.y * sc),
                  (_Float16)(v.z * sc), (_Float16)(v.w * sc) };
      *(half4*)&As[r * LDH + fcol] = h;
    }
    #pragma unroll
    for (int s = 0; s < 8; s++) {
      int r = frow + s * 16;
      float4 v = *(const float4*)&Vb[(size_t)(j0 + r) * DD + kb + fcol];
      float sc = inv_nv[b * TV + j0 + r];
      half4 h = { (_Float16)(v.x * sc), (_Float16)(v.y * sc),
                  (_Float16)(v.z * sc), (_Float16)(v.w * sc) };
      *(half4*)&Bs[r * LDH + fcol] = h;
    }
    __syncthreads();
    #pragma unroll
    for (int ks = 0; ks < 2; ks++) {
      half8 af[4], bf[4];
      #pragma unroll
      for (int mf = 0; mf < 4; mf++)
        af[mf] = *(const half8*)&As[(wm * 64 + mf * 16 + l16) * LDH + ks * 32 + lq * 8];
      #pragma unroll
      for (int nf = 0; nf < 4; nf++)
        bf[nf] = *(const half8*)&Bs[(wn * 64 + nf * 16 + l16) * LDH + ks * 32 + lq * 8];
      #pragma unroll
      for (int mf = 0; mf < 4; mf++)
        #pragma unroll
        for (int nf = 0; nf < 4; nf++)
          acc[mf][nf] = __builtin_amdgcn_mfma_f32_16x16x32_f16(af[mf], bf[nf], acc[mf][nf], 0, 0, 0);
    }
  }

  float lt = *lam_t;
  float c1 = LOG2E / EPSI;
  #pragma unroll
  for (int mf = 0; mf < 4; mf++)
    #pragma unroll
    for (int nf = 0; nf < 4; nf++)
      #pragma unroll
      for (int r = 0; r < 4; r++) {
        int a = a0 + wm * 64 + mf * 16 + lq * 4 + r;
        int j = j0 + wn * 64 + nf * 16 + l16;
        float sim = acc[mf][nf][r];
        float td = fabsf((float)a * (1.0f / TA) - (float)j * (1.0f / TV));
        float val = c1 * (sim - 1.0f - lt * td);
        size_t o = ((size_t)b * TA + a) * TV + j;
        if constexpr (F16) Kh[o] = (_Float16)val;
        else               Kb[o] = val;
      }
}

// ---------------- persistent cooperative Sinkhorn: K lives in VGPRs --------
// 256 blocks x 512 thr (8 waves), 1 block/CU. Wave holds 16 rows x 1024 cols
// of f16 K in 128 VGPRs for the whole 20-iteration loop + final softmax.
__global__ __launch_bounds__(512, 2) void coop_k(const _Float16* __restrict__ Kh,
                                                 float* __restrict__ Vp,
                                                 float* __restrict__ pc,
                                                 float* __restrict__ out) {
  namespace cg = cooperative_groups;
  cg::grid_group grid = cg::this_grid();
  __shared__ float lc[8][1024];
  const int tid  = threadIdx.x, lane = tid & 63, wid = tid >> 6;
  const int bid  = blockIdx.x;
  const int row0 = bid * 128 + wid * 16;   // wave's first global row
  const int b    = bid >> 4;               // batch (16 blocks per batch)
  const int col0 = lane * 16;

  // stage this wave's K rows into registers (16 rows x 16 cols f16 = 128 VGPR)
  half8 h[16][2];
  #pragma unroll
  for (int r = 0; r < 16; r++) {
    const _Float16* rp = Kh + (size_t)(row0 + r) * TV + col0;
    h[r][0] = *(const half8*)&rp[0];
    h[r][1] = *(const half8*)&rp[8];
  }

  for (int it = 0; it < NIT; it++) {
    float vpl[16];
    {
      const float* vp = Vp + b * TV + col0;
      #pragma unroll
      for (int q = 0; q < 4; q++) *(f32x4*)&vpl[q * 4] = *(const f32x4*)&vp[q * 4];
    }
    float C[16];
    #pragma unroll
    for (int i = 0; i < 16; i++) C[i] = 0.f;

    #pragma unroll
    for (int pr = 0; pr < 8; pr++) {   // process rows in pairs (interleave chains)
      float e0[16], e1[16];
      float s0 = 0.f, s1 = 0.f;
      #pragma unroll
      for (int i = 0; i < 16; i++) {
        e0[i] = exp2f((float)h[2 * pr + 0][i >> 3][i & 7] + vpl[i]);
        s0 += e0[i];
      }
      #pragma unroll
      for (int i = 0; i < 16; i++) {
        e1[i] = exp2f((float)h[2 * pr + 1][i >> 3][i & 7] + vpl[i]);
        s1 += e1[i];
      }
      #pragma unroll
      for (int m = 32; m; m >>= 1) {
        s0 += __shfl_xor(s0, m, 64);
        s1 += __shfl_xor(s1, m, 64);
      }
      float w0 = 1.0f / s0;
      float w1 = 1.0f / s1;
      #pragma unroll
      for (int i = 0; i < 16; i++)
        C[i] = fmaf(e1[i], w1, fmaf(e0[i], w0, C[i]));
    }

    // merge 8 waves' column partials -> pc[bid]
    #pragma unroll
    for (int q = 0; q < 4; q++)
      *(f32x4*)&lc[wid][col0 + q * 4] = *(f32x4*)&C[q * 4];
    __syncthreads();
    #pragma unroll
    for (int k2 = 0; k2 < 2; k2++) {
      int c2 = tid + k2 * 512;
      float S = 0.f;
      #pragma unroll
      for (int w = 0; w < 8; w++) S += lc[w][c2];
      pc[(size_t)bid * 1024 + c2] = S;
    }
    grid.sync();

    // phase B: each block updates its 64 Vp entries
    if (tid < 64) {
      int i  = bid * 64 + tid;
      int b2 = i >> 10, j = i & 1023;
      const float* p = pc + ((size_t)b2 * 16) * 1024 + j;
      float S = 0.f;
      #pragma unroll
      for (int c = 0; c < 16; c++) S += p[c * 1024];
      Vp[i] -= log2f(S);
    }
    grid.sync();
  }

  // final: transport = row-softmax(K + Vp_final), K still in registers
  float vpl[16];
  {
    const float* vp = Vp + b * TV + col0;
    #pragma unroll
    for (int q = 0; q < 4; q++) *(f32x4*)&vpl[q * 4] = *(const f32x4*)&vp[q * 4];
  }
  #pragma unroll 2
  for (int r = 0; r < 16; r++) {
    float e[16], s = 0.f;
    #pragma unroll
    for (int i = 0; i < 16; i++) {
      e[i] = exp2f((float)h[r][i >> 3][i & 7] + vpl[i]);
      s += e[i];
    }
    s = wave_sum(s);
    float w = 1.0f / s;
    float* o = out + (size_t)(row0 + r) * TV + col0;
    #pragma unroll
    for (int q = 0; q < 4; q++) {
      f32x4 ov = { e[q*4+0] * w, e[q*4+1] * w, e[q*4+2] * w, e[q*4+3] * w };
      *(f32x4*)&o[q * 4] = ov;
    }
  }
}

// ---------------- fallback loop kernels (round-3 path) ---------------------
__global__ __launch_bounds__(512) void iter16_k(const _Float16* __restrict__ Kh,
                                                const float* __restrict__ Vp,
                                                float* __restrict__ pc) {
  __shared__ float lc[8][1024];
  int tid = threadIdx.x, lane = tid & 63, wid = tid >> 6;
  int row0 = (blockIdx.x * 8 + wid) * 8;
  int b = row0 >> 11;
  const float* vp = Vp + b * TV + lane * 8;
  float vpl[16];
  *(float4*)&vpl[0]  = *(const float4*)&vp[0];
  *(float4*)&vpl[4]  = *(const float4*)&vp[4];
  *(float4*)&vpl[8]  = *(const float4*)&vp[512];
  *(float4*)&vpl[12] = *(const float4*)&vp[516];
  float C[16];
  #pragma unroll
  for (int i = 0; i < 16; i++) C[i] = 0.f;

  #pragma unroll 2
  for (int r = 0; r < 8; r++) {
    const _Float16* row = Kh + (size_t)(row0 + r) * TV + lane * 8;
    half8 h0 = *(const half8*)&row[0];
    half8 h1 = *(const half8*)&row[512];
    float e[16];
    float s = 0.f;
    #pragma unroll
    for (int i = 0; i < 8; i++) { e[i] = exp2f((float)h0[i] + vpl[i]); s += e[i]; }
    #pragma unroll
    for (int i = 0; i < 8; i++) { e[8 + i] = exp2f((float)h1[i] + vpl[8 + i]); s += e[8 + i]; }
    s = wave_sum(s);
    float w = 1.0f / s;
    #pragma unroll
    for (int i = 0; i < 16; i++) C[i] = fmaf(e[i], w, C[i]);
  }

  *(float4*)&lc[wid][lane * 8]           = make_float4(C[0], C[1], C[2], C[3]);
  *(float4*)&lc[wid][lane * 8 + 4]       = make_float4(C[4], C[5], C[6], C[7]);
  *(float4*)&lc[wid][512 + lane * 8]     = make_float4(C[8], C[9], C[10], C[11]);
  *(float4*)&lc[wid][512 + lane * 8 + 4] = make_float4(C[12], C[13], C[14], C[15]);
  __syncthreads();
  #pragma unroll
  for (int k = 0; k < 2; k++) {
    int col = tid + k * 512;
    float S = 0.f;
    #pragma unroll
    for (int w = 0; w < 8; w++) S += lc[w][col];
    pc[(size_t)blockIdx.x * 1024 + col] = S;
  }
}

__global__ __launch_bounds__(512) void iter32_k(const float* __restrict__ Kb,
                                                const float* __restrict__ Vp,
                                                float* __restrict__ pc) {
  __shared__ float lc[8][1024];
  int tid = threadIdx.x, lane = tid & 63, wid = tid >> 6;
  int row0 = (blockIdx.x * 8 + wid) * 8;
  int b = row0 >> 11;
  const float* vp = Vp + b * TV;
  float vpl[16];
  #pragma unroll
  for (int q = 0; q < 4; q++)
    *(float4*)&vpl[q * 4] = *(const float4*)&vp[q * 256 + lane * 4];
  float C[16];
  #pragma unroll
  for (int i = 0; i < 16; i++) C[i] = 0.f;

  #pragma unroll 2
  for (int r = 0; r < 8; r++) {
    const float* row = Kb + (size_t)(row0 + r) * TV;
    float e[16];
    float s = 0.f;
    #pragma unroll
    for (int q = 0; q < 4; q++) {
      float4 kv = *(const float4*)&row[q * 256 + lane * 4];
      e[q*4+0] = exp2f(kv.x + vpl[q*4+0]);
      e[q*4+1] = exp2f(kv.y + vpl[q*4+1]);
      e[q*4+2] = exp2f(kv.z + vpl[q*4+2]);
      e[q*4+3] = exp2f(kv.w + vpl[q*4+3]);
      s += e[q*4+0] + e[q*4+1] + e[q*4+2] + e[q*4+3];
    }
    s = wave_sum(s);
    float w = 1.0f / s;
    #pragma unroll
    for (int i = 0; i < 16; i++) C[i] = fmaf(e[i], w, C[i]);
  }

  #pragma unroll
  for (int q = 0; q < 4; q++)
    *(float4*)&lc[wid][q * 256 + lane * 4] =
        make_float4(C[q*4+0], C[q*4+1], C[q*4+2], C[q*4+3]);
  __syncthreads();
  #pragma unroll
  for (int k = 0; k < 2; k++) {
    int col = tid + k * 512;
    float S = 0.f;
    #pragma unroll
    for (int w = 0; w < 8; w++) S += lc[w][col];
    pc[(size_t)blockIdx.x * 1024 + col] = S;
  }
}

__global__ void vcomb_k(const float* __restrict__ pc, float* __restrict__ Vp) {
  int i = blockIdx.x * blockDim.x + threadIdx.x;
  int b = i >> 10, j = i & 1023;
  const float* p = pc + (size_t)(b * 32) * 1024 + j;
  float S = 0.f;
  #pragma unroll
  for (int c = 0; c < 32; c++) S += p[c * 1024];
  Vp[i] -= log2f(S);
}

__global__ __launch_bounds__(256) void final16_k(const _Float16* __restrict__ Kh,
                                                 const float* __restrict__ Vp,
                                                 float* __restrict__ out) {
  int gw   = (blockIdx.x * blockDim.x + threadIdx.x) >> 6;
  int lane = threadIdx.x & 63;
  int b = gw >> 11;
  const float* vp = Vp + b * TV + lane * 8;
  float vpl[16];
  *(float4*)&vpl[0]  = *(const float4*)&vp[0];
  *(float4*)&vpl[4]  = *(const float4*)&vp[4];
  *(float4*)&vpl[8]  = *(const float4*)&vp[512];
  *(float4*)&vpl[12] = *(const float4*)&vp[516];
  const _Float16* row = Kh + (size_t)gw * TV + lane * 8;
  half8 h0 = *(const half8*)&row[0];
  half8 h1 = *(const half8*)&row[512];
  float e[16];
  float s = 0.f;
  #pragma unroll
  for (int i = 0; i < 8; i++) { e[i] = exp2f((float)h0[i] + vpl[i]); s += e[i]; }
  #pragma unroll
  for (int i = 0; i < 8; i++) { e[8 + i] = exp2f((float)h1[i] + vpl[8 + i]); s += e[8 + i]; }
  s = wave_sum(s);
  float inv = 1.0f / s;
  float* o = out + (size_t)gw * TV + lane * 8;
  *(float4*)&o[0]   = make_float4(e[0] * inv, e[1] * inv, e[2] * inv, e[3] * inv);
  *(float4*)&o[4]   = make_float4(e[4] * inv, e[5] * inv, e[6] * inv, e[7] * inv);
  *(float4*)&o[512] = make_float4(e[8] * inv, e[9] * inv, e[10] * inv, e[11] * inv);
  *(float4*)&o[516] = make_float4(e[12] * inv, e[13] * inv, e[14] * inv, e[15] * inv);
}

__global__ __launch_bounds__(256) void final32_k(float* __restrict__ Kb,
                                                 const float* __restrict__ Vp) {
  int gw   = (blockIdx.x * blockDim.x + threadIdx.x) >> 6;
  int lane = threadIdx.x & 63;
  int b = gw >> 11;
  const float* vp = Vp + b * TV;
  float* row = Kb + (size_t)gw * TV;
  float e[16];
  float s = 0.f;
  #pragma unroll
  for (int q = 0; q < 4; q++) {
    float4 kv = *(const float4*)&row[q * 256 + lane * 4];
    float4 vv = *(const float4*)&vp[q * 256 + lane * 4];
    e[q*4+0] = exp2f(kv.x + vv.x); e[q*4+1] = exp2f(kv.y + vv.y);
    e[q*4+2] = exp2f(kv.z + vv.z); e[q*4+3] = exp2f(kv.w + vv.w);
    s += e[q*4+0] + e[q*4+1] + e[q*4+2] + e[q*4+3];
  }
  s = wave_sum(s);
  float inv = 1.0f / s;
  #pragma unroll
  for (int q = 0; q < 4; q++)
    *(float4*)&row[q * 256 + lane * 4] =
        make_float4(e[q*4+0] * inv, e[q*4+1] * inv, e[q*4+2] * inv, e[q*4+3] * inv);
}

extern "C" void kernel_launch(void* const* d_in, const int* in_sizes, int n_in,
                              void* d_out, int out_size, void* d_ws, size_t ws_size,
                              hipStream_t stream) {
  const float* audio   = (const float*)d_in[0];
  const float* video   = (const float*)d_in[1];
  const float* quality = (const float*)d_in[2];
  const float* lam_t   = (const float*)d_in[3];
  const float* lam_q   = (const float*)d_in[4];

  float* out = (float*)d_out;
  float* ws  = (float*)d_ws;
  float* inv_na = ws;                         // 32768
  float* inv_nv = ws + 32768;                 // 16384
  float* Vp     = ws + 49152;                 // 16384
  float* pc     = ws + 65536;                 // 524288 (coop uses first 256*1024)
  _Float16* Kh  = (_Float16*)(ws + 589824);   // 64 MiB

  size_t need_f16 = 589824ull * 4 + (size_t)B_ * TA * TV * 2;

  norms_k<<<12288, 256, 0, stream>>>(audio, video, inv_na, inv_nv);
  vinit_k<<<64, 256, 0, stream>>>(quality, lam_q, Vp);

  if (ws_size >= need_f16) {
    cost_k<true><<<dim3(16, 8, 16), 256, 0, stream>>>(audio, video, inv_na, inv_nv,
                                                      lam_t, nullptr, Kh);
    const _Float16* Khc = Kh;
    void* args[] = { (void*)&Khc, (void*)&Vp, (void*)&pc, (void*)&out };
    hipError_t err = hipLaunchCooperativeKernel((const void*)coop_k, dim3(256),
                                                dim3(512), args, 0, stream);
    if (err != hipSuccess) {
      for (int it = 0; it < NIT; it++) {
        iter16_k<<<512, 512, 0, stream>>>(Kh, Vp, pc);
        vcomb_k<<<64, 256, 0, stream>>>(pc, Vp);
      }
      final16_k<<<8192, 256, 0, stream>>>(Kh, Vp, out);
    }
  } else {
    float* Kb = out;
    cost_k<false><<<dim3(16, 8, 16), 256, 0, stream>>>(audio, video, inv_na, inv_nv,
                                                       lam_t, Kb, nullptr);
    for (int it = 0; it < NIT; it++) {
      iter32_k<<<512, 512, 0, stream>>>(Kb, Vp, pc);
      vcomb_k<<<64, 256, 0, stream>>>(pc, Vp);
    }
    final32_k<<<8192, 256, 0, stream>>>(Kb, Vp);
  }
}

// Round 5
// 2659.147 us; speedup vs baseline: 1.2380x; 1.2380x over previous
//
#include <hip/hip_runtime.h>
#include <hip/hip_fp16.h>
#include <hip/hip_cooperative_groups.h>

#define B_  16
#define TA  2048
#define TV  1024
#define DD  512
#define NIT 20

static constexpr float EPSI  = 0.15f;
static constexpr float LOG2E = 1.4426950408889634f;

using f32x4 = __attribute__((ext_vector_type(4))) float;
using half8 = __attribute__((ext_vector_type(8))) _Float16;
using half4 = __attribute__((ext_vector_type(4))) _Float16;

__device__ inline float wave_sum(float x) {
  #pragma unroll
  for (int m = 32; m; m >>= 1) x += __shfl_xor(x, m, 64);
  return x;
}

// bank-spread swizzle for stride-64B f32 vector access (flips bits 2-4 by row bits)
__device__ inline int swz(int c) { return c ^ (((c >> 5) & 7) << 2); }

// ---------------- norms: inv L2 norm per row (audio rows then video rows) ---
__global__ __launch_bounds__(256) void norms_k(const float* __restrict__ audio,
                                               const float* __restrict__ video,
                                               float* __restrict__ inv_na,
                                               float* __restrict__ inv_nv) {
  int wid  = (blockIdx.x * blockDim.x + threadIdx.x) >> 6;
  int lane = threadIdx.x & 63;
  const float* src;
  float* dst;
  if (wid < B_ * TA) { src = audio + (size_t)wid * DD; dst = inv_na + wid; }
  else               { src = video + (size_t)(wid - B_ * TA) * DD; dst = inv_nv + (wid - B_ * TA); }
  const float4* s4 = (const float4*)src;
  float ss = 0.f;
  #pragma unroll
  for (int i = 0; i < 2; i++) {
    float4 v = s4[lane + i * 64];
    ss += v.x * v.x + v.y * v.y + v.z * v.z + v.w * v.w;
  }
  ss = wave_sum(ss);
  if (lane == 0) *dst = 1.0f / fmaxf(sqrtf(ss), 1e-12f);
}

// ---------------- v' init: v' = -c1 * lam_q * (1 - quality) ----------------
__global__ void vinit_k(const float* __restrict__ quality,
                        const float* __restrict__ lam_q,
                        float* __restrict__ Vp) {
  int i = blockIdx.x * blockDim.x + threadIdx.x;  // 0..B_*TV-1
  float c1 = LOG2E / EPSI;
  Vp[i] = -c1 * (*lam_q) * (1.0f - quality[i]);
}

// ---------------- cost GEMM: Ksmall2 = c1*(sim - 1 - lt*timedist) ----------
#define BM 128
#define BN 128
#define BK 64
#define LDH 72

template<bool F16>
__global__ __launch_bounds__(256) void cost_k(const float* __restrict__ audio,
                                              const float* __restrict__ video,
                                              const float* __restrict__ inv_na,
                                              const float* __restrict__ inv_nv,
                                              const float* __restrict__ lam_t,
                                              float* __restrict__ Kb,
                                              _Float16* __restrict__ Kh) {
  __shared__ _Float16 As[BM * LDH];
  __shared__ _Float16 Bs[BN * LDH];
  int b  = blockIdx.z;
  int a0 = blockIdx.x * BM;
  int j0 = blockIdx.y * BN;
  int tid  = threadIdx.x;
  int lane = tid & 63;
  int wid  = tid >> 6;
  int wm = wid >> 1, wn = wid & 1;

  const float* Ab = audio + (size_t)b * TA * DD;
  const float* Vb = video + (size_t)b * TV * DD;

  f32x4 acc[4][4];
  #pragma unroll
  for (int i = 0; i < 4; i++)
    #pragma unroll
    for (int j = 0; j < 4; j++)
      #pragma unroll
      for (int r = 0; r < 4; r++) acc[i][j][r] = 0.f;

  int frow = tid >> 4;
  int fcol = (tid & 15) * 4;
  int l16 = lane & 15, lq = lane >> 4;

  for (int kb = 0; kb < DD; kb += BK) {
    __syncthreads();
    #pragma unroll
    for (int s = 0; s < 8; s++) {
      int r = frow + s * 16;
      float4 v = *(const float4*)&Ab[(size_t)(a0 + r) * DD + kb + fcol];
      float sc = inv_na[b * TA + a0 + r];
      half4 h = { (_Float16)(v.x * sc), (_Float16)(v.y * sc),
                  (_Float16)(v.z * sc), (_Float16)(v.w * sc) };
      *(half4*)&As[r * LDH + fcol] = h;
    }
    #pragma unroll
    for (int s = 0; s < 8; s++) {
      int r = frow + s * 16;
      float4 v = *(const float4*)&Vb[(size_t)(j0 + r) * DD + kb + fcol];
      float sc = inv_nv[b * TV + j0 + r];
      half4 h = { (_Float16)(v.x * sc), (_Float16)(v.y * sc),
                  (_Float16)(v.z * sc), (_Float16)(v.w * sc) };
      *(half4*)&Bs[r * LDH + fcol] = h;
    }
    __syncthreads();
    #pragma unroll
    for (int ks = 0; ks < 2; ks++) {
      half8 af[4], bf[4];
      #pragma unroll
      for (int mf = 0; mf < 4; mf++)
        af[mf] = *(const half8*)&As[(wm * 64 + mf * 16 + l16) * LDH + ks * 32 + lq * 8];
      #pragma unroll
      for (int nf = 0; nf < 4; nf++)
        bf[nf] = *(const half8*)&Bs[(wn * 64 + nf * 16 + l16) * LDH + ks * 32 + lq * 8];
      #pragma unroll
      for (int mf = 0; mf < 4; mf++)
        #pragma unroll
        for (int nf = 0; nf < 4; nf++)
          acc[mf][nf] = __builtin_amdgcn_mfma_f32_16x16x32_f16(af[mf], bf[nf], acc[mf][nf], 0, 0, 0);
    }
  }

  float lt = *lam_t;
  float c1 = LOG2E / EPSI;
  #pragma unroll
  for (int mf = 0; mf < 4; mf++)
    #pragma unroll
    for (int nf = 0; nf < 4; nf++)
      #pragma unroll
      for (int r = 0; r < 4; r++) {
        int a = a0 + wm * 64 + mf * 16 + lq * 4 + r;
        int j = j0 + wn * 64 + nf * 16 + l16;
        float sim = acc[mf][nf][r];
        float td = fabsf((float)a * (1.0f / TA) - (float)j * (1.0f / TV));
        float val = c1 * (sim - 1.0f - lt * td);
        size_t o = ((size_t)b * TA + a) * TV + j;
        if constexpr (F16) Kh[o] = (_Float16)val;
        else               Kb[o] = val;
      }
}

// ---------------- persistent cooperative Sinkhorn: K lives in VGPRs --------
// 256 blocks x 512 thr (8 waves), 1 block/CU, launch_bounds(512,1) -> 256-VGPR
// budget. Wave holds 16 rows x 16 cols/lane of f16 K (128 VGPR) all 20 iters.
// One grid.sync per iteration (double-buffered pc; Vp kept in block-local LDS).
__global__ __launch_bounds__(512, 1) void coop_k(const _Float16* __restrict__ Kh,
                                                 const float* __restrict__ Vp0,
                                                 float* __restrict__ pc,
                                                 float* __restrict__ out) {
  namespace cg = cooperative_groups;
  cg::grid_group grid = cg::this_grid();
  __shared__ float lc[8][1024];
  __shared__ float vbuf[1024];
  const int tid  = threadIdx.x, lane = tid & 63, wid = tid >> 6;
  const int bid  = blockIdx.x;
  const int row0 = bid * 128 + wid * 16;   // wave's first global row
  const int b    = bid >> 4;               // batch (16 blocks per batch)
  const int col0 = lane * 16;

  // block-local copy of this batch's Vp (swizzled storage)
  if (tid < 256) {
    f32x4 v = *(const f32x4*)&Vp0[b * TV + tid * 4];
    *(f32x4*)&vbuf[swz(tid * 4)] = v;
  }

  // stage this wave's K rows into registers (16 rows x 16 cols f16 = 128 VGPR)
  half8 h[16][2];
  #pragma unroll
  for (int r = 0; r < 16; r++) {
    const _Float16* rp = Kh + (size_t)(row0 + r) * TV + col0;
    h[r][0] = *(const half8*)&rp[0];
    h[r][1] = *(const half8*)&rp[8];
  }
  __syncthreads();

  float vpl[16];
  #pragma unroll
  for (int q = 0; q < 4; q++)
    *(f32x4*)&vpl[q * 4] = *(const f32x4*)&vbuf[swz(col0 + q * 4)];

  for (int it = 0; it < NIT; it++) {
    float* pcb = pc + (size_t)(it & 1) * (256 * 1024);
    float C[16];
    #pragma unroll
    for (int i = 0; i < 16; i++) C[i] = 0.f;

    #pragma unroll
    for (int r = 0; r < 16; r++) {
      float e[16];
      float s = 0.f;
      #pragma unroll
      for (int i = 0; i < 16; i++) {
        e[i] = exp2f((float)h[r][i >> 3][i & 7] + vpl[i]);
        s += e[i];
      }
      s = wave_sum(s);
      float w = 1.0f / s;
      #pragma unroll
      for (int i = 0; i < 16; i++) C[i] = fmaf(e[i], w, C[i]);
    }

    // merge 8 waves' column partials in LDS (swizzled to spread banks)
    #pragma unroll
    for (int q = 0; q < 4; q++)
      *(f32x4*)&lc[wid][swz(col0 + q * 4)] = *(f32x4*)&C[q * 4];
    __syncthreads();
    #pragma unroll
    for (int k2 = 0; k2 < 2; k2++) {
      int col = tid + k2 * 512;
      int sc_ = swz(col);
      float S = 0.f;
      #pragma unroll
      for (int w = 0; w < 8; w++) S += lc[w][sc_];
      pcb[(size_t)bid * 1024 + col] = S;
    }
    grid.sync();

    // every block redundantly reduces its batch's 16 partials -> local Vp
    #pragma unroll
    for (int k2 = 0; k2 < 2; k2++) {
      int col = tid + k2 * 512;
      const float* p = pcb + (size_t)(b * 16) * 1024 + col;
      float S = 0.f;
      #pragma unroll
      for (int c = 0; c < 16; c++) S += p[c * 1024];
      vbuf[swz(col)] -= log2f(S);
    }
    __syncthreads();
    #pragma unroll
    for (int q = 0; q < 4; q++)
      *(f32x4*)&vpl[q * 4] = *(const f32x4*)&vbuf[swz(col0 + q * 4)];
  }

  // final: transport = row-softmax(K + Vp_final), K still in registers
  #pragma unroll 2
  for (int r = 0; r < 16; r++) {
    float e[16], s = 0.f;
    #pragma unroll
    for (int i = 0; i < 16; i++) {
      e[i] = exp2f((float)h[r][i >> 3][i & 7] + vpl[i]);
      s += e[i];
    }
    s = wave_sum(s);
    float w = 1.0f / s;
    float* o = out + (size_t)(row0 + r) * TV + col0;
    #pragma unroll
    for (int q = 0; q < 4; q++) {
      f32x4 ov = { e[q*4+0] * w, e[q*4+1] * w, e[q*4+2] * w, e[q*4+3] * w };
      *(f32x4*)&o[q * 4] = ov;
    }
  }
}

// ---------------- fallback loop kernels (round-3 path) ---------------------
__global__ __launch_bounds__(512) void iter16_k(const _Float16* __restrict__ Kh,
                                                const float* __restrict__ Vp,
                                                float* __restrict__ pc) {
  __shared__ float lc[8][1024];
  int tid = threadIdx.x, lane = tid & 63, wid = tid >> 6;
  int row0 = (blockIdx.x * 8 + wid) * 8;
  int b = row0 >> 11;
  const float* vp = Vp + b * TV + lane * 8;
  float vpl[16];
  *(float4*)&vpl[0]  = *(const float4*)&vp[0];
  *(float4*)&vpl[4]  = *(const float4*)&vp[4];
  *(float4*)&vpl[8]  = *(const float4*)&vp[512];
  *(float4*)&vpl[12] = *(const float4*)&vp[516];
  float C[16];
  #pragma unroll
  for (int i = 0; i < 16; i++) C[i] = 0.f;

  #pragma unroll 2
  for (int r = 0; r < 8; r++) {
    const _Float16* row = Kh + (size_t)(row0 + r) * TV + lane * 8;
    half8 h0 = *(const half8*)&row[0];
    half8 h1 = *(const half8*)&row[512];
    float e[16];
    float s = 0.f;
    #pragma unroll
    for (int i = 0; i < 8; i++) { e[i] = exp2f((float)h0[i] + vpl[i]); s += e[i]; }
    #pragma unroll
    for (int i = 0; i < 8; i++) { e[8 + i] = exp2f((float)h1[i] + vpl[8 + i]); s += e[8 + i]; }
    s = wave_sum(s);
    float w = 1.0f / s;
    #pragma unroll
    for (int i = 0; i < 16; i++) C[i] = fmaf(e[i], w, C[i]);
  }

  *(float4*)&lc[wid][lane * 8]           = make_float4(C[0], C[1], C[2], C[3]);
  *(float4*)&lc[wid][lane * 8 + 4]       = make_float4(C[4], C[5], C[6], C[7]);
  *(float4*)&lc[wid][512 + lane * 8]     = make_float4(C[8], C[9], C[10], C[11]);
  *(float4*)&lc[wid][512 + lane * 8 + 4] = make_float4(C[12], C[13], C[14], C[15]);
  __syncthreads();
  #pragma unroll
  for (int k = 0; k < 2; k++) {
    int col = tid + k * 512;
    float S = 0.f;
    #pragma unroll
    for (int w = 0; w < 8; w++) S += lc[w][col];
    pc[(size_t)blockIdx.x * 1024 + col] = S;
  }
}

__global__ __launch_bounds__(512) void iter32_k(const float* __restrict__ Kb,
                                                const float* __restrict__ Vp,
                                                float* __restrict__ pc) {
  __shared__ float lc[8][1024];
  int tid = threadIdx.x, lane = tid & 63, wid = tid >> 6;
  int row0 = (blockIdx.x * 8 + wid) * 8;
  int b = row0 >> 11;
  const float* vp = Vp + b * TV;
  float vpl[16];
  #pragma unroll
  for (int q = 0; q < 4; q++)
    *(float4*)&vpl[q * 4] = *(const float4*)&vp[q * 256 + lane * 4];
  float C[16];
  #pragma unroll
  for (int i = 0; i < 16; i++) C[i] = 0.f;

  #pragma unroll 2
  for (int r = 0; r < 8; r++) {
    const float* row = Kb + (size_t)(row0 + r) * TV;
    float e[16];
    float s = 0.f;
    #pragma unroll
    for (int q = 0; q < 4; q++) {
      float4 kv = *(const float4*)&row[q * 256 + lane * 4];
      e[q*4+0] = exp2f(kv.x + vpl[q*4+0]);
      e[q*4+1] = exp2f(kv.y + vpl[q*4+1]);
      e[q*4+2] = exp2f(kv.z + vpl[q*4+2]);
      e[q*4+3] = exp2f(kv.w + vpl[q*4+3]);
      s += e[q*4+0] + e[q*4+1] + e[q*4+2] + e[q*4+3];
    }
    s = wave_sum(s);
    float w = 1.0f / s;
    #pragma unroll
    for (int i = 0; i < 16; i++) C[i] = fmaf(e[i], w, C[i]);
  }

  #pragma unroll
  for (int q = 0; q < 4; q++)
    *(float4*)&lc[wid][q * 256 + lane * 4] =
        make_float4(C[q*4+0], C[q*4+1], C[q*4+2], C[q*4+3]);
  __syncthreads();
  #pragma unroll
  for (int k = 0; k < 2; k++) {
    int col = tid + k * 512;
    float S = 0.f;
    #pragma unroll
    for (int w = 0; w < 8; w++) S += lc[w][col];
    pc[(size_t)blockIdx.x * 1024 + col] = S;
  }
}

__global__ void vcomb_k(const float* __restrict__ pc, float* __restrict__ Vp) {
  int i = blockIdx.x * blockDim.x + threadIdx.x;
  int b = i >> 10, j = i & 1023;
  const float* p = pc + (size_t)(b * 32) * 1024 + j;
  float S = 0.f;
  #pragma unroll
  for (int c = 0; c < 32; c++) S += p[c * 1024];
  Vp[i] -= log2f(S);
}

__global__ __launch_bounds__(256) void final16_k(const _Float16* __restrict__ Kh,
                                                 const float* __restrict__ Vp,
                                                 float* __restrict__ out) {
  int gw   = (blockIdx.x * blockDim.x + threadIdx.x) >> 6;
  int lane = threadIdx.x & 63;
  int b = gw >> 11;
  const float* vp = Vp + b * TV + lane * 8;
  float vpl[16];
  *(float4*)&vpl[0]  = *(const float4*)&vp[0];
  *(float4*)&vpl[4]  = *(const float4*)&vp[4];
  *(float4*)&vpl[8]  = *(const float4*)&vp[512];
  *(float4*)&vpl[12] = *(const float4*)&vp[516];
  const _Float16* row = Kh + (size_t)gw * TV + lane * 8;
  half8 h0 = *(const half8*)&row[0];
  half8 h1 = *(const half8*)&row[512];
  float e[16];
  float s = 0.f;
  #pragma unroll
  for (int i = 0; i < 8; i++) { e[i] = exp2f((float)h0[i] + vpl[i]); s += e[i]; }
  #pragma unroll
  for (int i = 0; i < 8; i++) { e[8 + i] = exp2f((float)h1[i] + vpl[8 + i]); s += e[8 + i]; }
  s = wave_sum(s);
  float inv = 1.0f / s;
  float* o = out + (size_t)gw * TV + lane * 8;
  *(float4*)&o[0]   = make_float4(e[0] * inv, e[1] * inv, e[2] * inv, e[3] * inv);
  *(float4*)&o[4]   = make_float4(e[4] * inv, e[5] * inv, e[6] * inv, e[7] * inv);
  *(float4*)&o[512] = make_float4(e[8] * inv, e[9] * inv, e[10] * inv, e[11] * inv);
  *(float4*)&o[516] = make_float4(e[12] * inv, e[13] * inv, e[14] * inv, e[15] * inv);
}

__global__ __launch_bounds__(256) void final32_k(float* __restrict__ Kb,
                                                 const float* __restrict__ Vp) {
  int gw   = (blockIdx.x * blockDim.x + threadIdx.x) >> 6;
  int lane = threadIdx.x & 63;
  int b = gw >> 11;
  const float* vp = Vp + b * TV;
  float* row = Kb + (size_t)gw * TV;
  float e[16];
  float s = 0.f;
  #pragma unroll
  for (int q = 0; q < 4; q++) {
    float4 kv = *(const float4*)&row[q * 256 + lane * 4];
    float4 vv = *(const float4*)&vp[q * 256 + lane * 4];
    e[q*4+0] = exp2f(kv.x + vv.x); e[q*4+1] = exp2f(kv.y + vv.y);
    e[q*4+2] = exp2f(kv.z + vv.z); e[q*4+3] = exp2f(kv.w + vv.w);
    s += e[q*4+0] + e[q*4+1] + e[q*4+2] + e[q*4+3];
  }
  s = wave_sum(s);
  float inv = 1.0f / s;
  #pragma unroll
  for (int q = 0; q < 4; q++)
    *(float4*)&row[q * 256 + lane * 4] =
        make_float4(e[q*4+0] * inv, e[q*4+1] * inv, e[q*4+2] * inv, e[q*4+3] * inv);
}

extern "C" void kernel_launch(void* const* d_in, const int* in_sizes, int n_in,
                              void* d_out, int out_size, void* d_ws, size_t ws_size,
                              hipStream_t stream) {
  const float* audio   = (const float*)d_in[0];
  const float* video   = (const float*)d_in[1];
  const float* quality = (const float*)d_in[2];
  const float* lam_t   = (const float*)d_in[3];
  const float* lam_q   = (const float*)d_in[4];

  float* out = (float*)d_out;
  float* ws  = (float*)d_ws;
  float* inv_na = ws;                         // 32768
  float* inv_nv = ws + 32768;                 // 16384
  float* Vp     = ws + 49152;                 // 16384
  float* pc     = ws + 65536;                 // 524288 (coop: 2 x 256*1024)
  _Float16* Kh  = (_Float16*)(ws + 589824);   // 64 MiB

  size_t need_f16 = 589824ull * 4 + (size_t)B_ * TA * TV * 2;

  norms_k<<<12288, 256, 0, stream>>>(audio, video, inv_na, inv_nv);
  vinit_k<<<64, 256, 0, stream>>>(quality, lam_q, Vp);

  if (ws_size >= need_f16) {
    cost_k<true><<<dim3(16, 8, 16), 256, 0, stream>>>(audio, video, inv_na, inv_nv,
                                                      lam_t, nullptr, Kh);
    const _Float16* Khc = Kh;
    const float* Vpc = Vp;
    void* args[] = { (void*)&Khc, (void*)&Vpc, (void*)&pc, (void*)&out };
    hipError_t err = hipLaunchCooperativeKernel((const void*)coop_k, dim3(256),
                                                dim3(512), args, 0, stream);
    if (err != hipSuccess) {
      for (int it = 0; it < NIT; it++) {
        iter16_k<<<512, 512, 0, stream>>>(Kh, Vp, pc);
        vcomb_k<<<64, 256, 0, stream>>>(pc, Vp);
      }
      final16_k<<<8192, 256, 0, stream>>>(Kh, Vp, out);
    }
  } else {
    float* Kb = out;
    cost_k<false><<<dim3(16, 8, 16), 256, 0, stream>>>(audio, video, inv_na, inv_nv,
                                                       lam_t, Kb, nullptr);
    for (int it = 0; it < NIT; it++) {
      iter32_k<<<512, 512, 0, stream>>>(Kb, Vp, pc);
      vcomb_k<<<64, 256, 0, stream>>>(pc, Vp);
    }
    final32_k<<<8192, 256, 0, stream>>>(Kb, Vp);
  }
}

// Round 6
// 2005.885 us; speedup vs baseline: 1.6412x; 1.3257x over previous
//
#include <hip/hip_runtime.h>
#include <hip/hip_fp16.h>
#include <hip/hip_cooperative_groups.h>

#define B_  16
#define TA  2048
#define TV  1024
#define DD  512
#define NIT 20

static constexpr float EPSI  = 0.15f;
static constexpr float LOG2E = 1.4426950408889634f;

using f32x4 = __attribute__((ext_vector_type(4))) float;
using half8 = __attribute__((ext_vector_type(8))) _Float16;
using half4 = __attribute__((ext_vector_type(4))) _Float16;

__device__ inline float wave_sum(float x) {
  #pragma unroll
  for (int m = 32; m; m >>= 1) x += __shfl_xor(x, m, 64);
  return x;
}

// bank-spread swizzle for stride-64B f32 vector access (flips bits 2-4 by row bits)
__device__ inline int swz(int c) { return c ^ (((c >> 5) & 7) << 2); }

// ---------------- norms: inv L2 norm per row (audio rows then video rows) ---
__global__ __launch_bounds__(256) void norms_k(const float* __restrict__ audio,
                                               const float* __restrict__ video,
                                               float* __restrict__ inv_na,
                                               float* __restrict__ inv_nv) {
  int wid  = (blockIdx.x * blockDim.x + threadIdx.x) >> 6;
  int lane = threadIdx.x & 63;
  const float* src;
  float* dst;
  if (wid < B_ * TA) { src = audio + (size_t)wid * DD; dst = inv_na + wid; }
  else               { src = video + (size_t)(wid - B_ * TA) * DD; dst = inv_nv + (wid - B_ * TA); }
  const float4* s4 = (const float4*)src;
  float ss = 0.f;
  #pragma unroll
  for (int i = 0; i < 2; i++) {
    float4 v = s4[lane + i * 64];
    ss += v.x * v.x + v.y * v.y + v.z * v.z + v.w * v.w;
  }
  ss = wave_sum(ss);
  if (lane == 0) *dst = 1.0f / fmaxf(sqrtf(ss), 1e-12f);
}

// ---------------- v' init: v' = -c1 * lam_q * (1 - quality) ----------------
__global__ void vinit_k(const float* __restrict__ quality,
                        const float* __restrict__ lam_q,
                        float* __restrict__ Vp) {
  int i = blockIdx.x * blockDim.x + threadIdx.x;  // 0..B_*TV-1
  float c1 = LOG2E / EPSI;
  Vp[i] = -c1 * (*lam_q) * (1.0f - quality[i]);
}

// ---------------- cost GEMM: Ksmall2 = c1*(sim - 1 - lt*timedist) ----------
#define BM 128
#define BN 128
#define BK 64
#define LDH 72

template<bool F16>
__global__ __launch_bounds__(256) void cost_k(const float* __restrict__ audio,
                                              const float* __restrict__ video,
                                              const float* __restrict__ inv_na,
                                              const float* __restrict__ inv_nv,
                                              const float* __restrict__ lam_t,
                                              float* __restrict__ Kb,
                                              _Float16* __restrict__ Kh) {
  __shared__ _Float16 As[BM * LDH];
  __shared__ _Float16 Bs[BN * LDH];
  int b  = blockIdx.z;
  int a0 = blockIdx.x * BM;
  int j0 = blockIdx.y * BN;
  int tid  = threadIdx.x;
  int lane = tid & 63;
  int wid  = tid >> 6;
  int wm = wid >> 1, wn = wid & 1;

  const float* Ab = audio + (size_t)b * TA * DD;
  const float* Vb = video + (size_t)b * TV * DD;

  f32x4 acc[4][4];
  #pragma unroll
  for (int i = 0; i < 4; i++)
    #pragma unroll
    for (int j = 0; j < 4; j++)
      #pragma unroll
      for (int r = 0; r < 4; r++) acc[i][j][r] = 0.f;

  int frow = tid >> 4;
  int fcol = (tid & 15) * 4;
  int l16 = lane & 15, lq = lane >> 4;

  for (int kb = 0; kb < DD; kb += BK) {
    __syncthreads();
    #pragma unroll
    for (int s = 0; s < 8; s++) {
      int r = frow + s * 16;
      float4 v = *(const float4*)&Ab[(size_t)(a0 + r) * DD + kb + fcol];
      float sc = inv_na[b * TA + a0 + r];
      half4 h = { (_Float16)(v.x * sc), (_Float16)(v.y * sc),
                  (_Float16)(v.z * sc), (_Float16)(v.w * sc) };
      *(half4*)&As[r * LDH + fcol] = h;
    }
    #pragma unroll
    for (int s = 0; s < 8; s++) {
      int r = frow + s * 16;
      float4 v = *(const float4*)&Vb[(size_t)(j0 + r) * DD + kb + fcol];
      float sc = inv_nv[b * TV + j0 + r];
      half4 h = { (_Float16)(v.x * sc), (_Float16)(v.y * sc),
                  (_Float16)(v.z * sc), (_Float16)(v.w * sc) };
      *(half4*)&Bs[r * LDH + fcol] = h;
    }
    __syncthreads();
    #pragma unroll
    for (int ks = 0; ks < 2; ks++) {
      half8 af[4], bf[4];
      #pragma unroll
      for (int mf = 0; mf < 4; mf++)
        af[mf] = *(const half8*)&As[(wm * 64 + mf * 16 + l16) * LDH + ks * 32 + lq * 8];
      #pragma unroll
      for (int nf = 0; nf < 4; nf++)
        bf[nf] = *(const half8*)&Bs[(wn * 64 + nf * 16 + l16) * LDH + ks * 32 + lq * 8];
      #pragma unroll
      for (int mf = 0; mf < 4; mf++)
        #pragma unroll
        for (int nf = 0; nf < 4; nf++)
          acc[mf][nf] = __builtin_amdgcn_mfma_f32_16x16x32_f16(af[mf], bf[nf], acc[mf][nf], 0, 0, 0);
    }
  }

  float lt = *lam_t;
  float c1 = LOG2E / EPSI;
  #pragma unroll
  for (int mf = 0; mf < 4; mf++)
    #pragma unroll
    for (int nf = 0; nf < 4; nf++)
      #pragma unroll
      for (int r = 0; r < 4; r++) {
        int a = a0 + wm * 64 + mf * 16 + lq * 4 + r;
        int j = j0 + wn * 64 + nf * 16 + l16;
        float sim = acc[mf][nf][r];
        float td = fabsf((float)a * (1.0f / TA) - (float)j * (1.0f / TV));
        float val = c1 * (sim - 1.0f - lt * td);
        size_t o = ((size_t)b * TA + a) * TV + j;
        if constexpr (F16) Kh[o] = (_Float16)val;
        else               Kb[o] = val;
      }
}

// ---------------- persistent cooperative Sinkhorn: K lives in VGPRs --------
// 256 blocks x 1024 thr (16 waves), 1 block/CU. The 1024-thread block forces
// the compiler to fit <=128 VGPR/wave (16 waves must fit 2048-reg pool).
// Wave holds 8 rows x 16 cols/lane of f16 K = 64 VGPR; live set ~122.
// One grid.sync per iteration; Vp in block-local LDS; pc double-buffered.
__global__ __launch_bounds__(1024, 1) void coop_k(const _Float16* __restrict__ Kh,
                                                  const float* __restrict__ Vp0,
                                                  float* __restrict__ pc,
                                                  float* __restrict__ out) {
  namespace cg = cooperative_groups;
  cg::grid_group grid = cg::this_grid();
  __shared__ float lc[16][1024];
  __shared__ float vbuf[1024];
  const int tid  = threadIdx.x, lane = tid & 63, wid = tid >> 6;  // wid 0..15
  const int bid  = blockIdx.x;
  const int row0 = bid * 128 + wid * 8;    // wave's first global row
  const int b    = bid >> 4;               // batch (16 blocks per batch)
  const int col0 = lane * 16;

  // block-local copy of this batch's Vp (swizzled storage)
  if (tid < 256) {
    f32x4 v = *(const f32x4*)&Vp0[b * TV + tid * 4];
    *(f32x4*)&vbuf[swz(tid * 4)] = v;
  }

  // stage this wave's K rows into registers (8 rows x 16 cols f16 = 64 VGPR)
  half8 h[8][2];
  #pragma unroll
  for (int r = 0; r < 8; r++) {
    const _Float16* rp = Kh + (size_t)(row0 + r) * TV + col0;
    h[r][0] = *(const half8*)&rp[0];
    h[r][1] = *(const half8*)&rp[8];
  }
  __syncthreads();

  float vpl[16];
  #pragma unroll
  for (int q = 0; q < 4; q++)
    *(f32x4*)&vpl[q * 4] = *(const f32x4*)&vbuf[swz(col0 + q * 4)];

  for (int it = 0; it < NIT; it++) {
    float* pcb = pc + (size_t)(it & 1) * (256 * 1024);
    float C[16];
    #pragma unroll
    for (int i = 0; i < 16; i++) C[i] = 0.f;

    #pragma unroll
    for (int r = 0; r < 8; r++) {
      float e[16];
      float s = 0.f;
      #pragma unroll
      for (int i = 0; i < 16; i++) {
        e[i] = exp2f((float)h[r][i >> 3][i & 7] + vpl[i]);
        s += e[i];
      }
      s = wave_sum(s);
      float w = 1.0f / s;
      #pragma unroll
      for (int i = 0; i < 16; i++) C[i] = fmaf(e[i], w, C[i]);
    }

    // merge 16 waves' column partials in LDS (swizzled to spread banks)
    #pragma unroll
    for (int q = 0; q < 4; q++)
      *(f32x4*)&lc[wid][swz(col0 + q * 4)] = *(f32x4*)&C[q * 4];
    __syncthreads();
    {
      int col = tid;               // 1024 threads, 1024 cols
      int sc_ = swz(col);
      float S = 0.f;
      #pragma unroll
      for (int w = 0; w < 16; w++) S += lc[w][sc_];
      pcb[(size_t)bid * 1024 + col] = S;
    }
    grid.sync();

    // every block redundantly reduces its batch's 16 partials -> local Vp
    {
      int col = tid;
      const float* p = pcb + (size_t)(b * 16) * 1024 + col;
      float S = 0.f;
      #pragma unroll
      for (int c = 0; c < 16; c++) S += p[c * 1024];
      vbuf[swz(col)] -= log2f(S);
    }
    __syncthreads();
    #pragma unroll
    for (int q = 0; q < 4; q++)
      *(f32x4*)&vpl[q * 4] = *(const f32x4*)&vbuf[swz(col0 + q * 4)];
  }

  // final: transport = row-softmax(K + Vp_final), K still in registers
  #pragma unroll 2
  for (int r = 0; r < 8; r++) {
    float e[16], s = 0.f;
    #pragma unroll
    for (int i = 0; i < 16; i++) {
      e[i] = exp2f((float)h[r][i >> 3][i & 7] + vpl[i]);
      s += e[i];
    }
    s = wave_sum(s);
    float w = 1.0f / s;
    float* o = out + (size_t)(row0 + r) * TV + col0;
    #pragma unroll
    for (int q = 0; q < 4; q++) {
      f32x4 ov = { e[q*4+0] * w, e[q*4+1] * w, e[q*4+2] * w, e[q*4+3] * w };
      *(f32x4*)&o[q * 4] = ov;
    }
  }
}

// ---------------- fallback loop kernels (round-3 path) ---------------------
__global__ __launch_bounds__(512) void iter16_k(const _Float16* __restrict__ Kh,
                                                const float* __restrict__ Vp,
                                                float* __restrict__ pc) {
  __shared__ float lc[8][1024];
  int tid = threadIdx.x, lane = tid & 63, wid = tid >> 6;
  int row0 = (blockIdx.x * 8 + wid) * 8;
  int b = row0 >> 11;
  const float* vp = Vp + b * TV + lane * 8;
  float vpl[16];
  *(float4*)&vpl[0]  = *(const float4*)&vp[0];
  *(float4*)&vpl[4]  = *(const float4*)&vp[4];
  *(float4*)&vpl[8]  = *(const float4*)&vp[512];
  *(float4*)&vpl[12] = *(const float4*)&vp[516];
  float C[16];
  #pragma unroll
  for (int i = 0; i < 16; i++) C[i] = 0.f;

  #pragma unroll 2
  for (int r = 0; r < 8; r++) {
    const _Float16* row = Kh + (size_t)(row0 + r) * TV + lane * 8;
    half8 h0 = *(const half8*)&row[0];
    half8 h1 = *(const half8*)&row[512];
    float e[16];
    float s = 0.f;
    #pragma unroll
    for (int i = 0; i < 8; i++) { e[i] = exp2f((float)h0[i] + vpl[i]); s += e[i]; }
    #pragma unroll
    for (int i = 0; i < 8; i++) { e[8 + i] = exp2f((float)h1[i] + vpl[8 + i]); s += e[8 + i]; }
    s = wave_sum(s);
    float w = 1.0f / s;
    #pragma unroll
    for (int i = 0; i < 16; i++) C[i] = fmaf(e[i], w, C[i]);
  }

  *(float4*)&lc[wid][lane * 8]           = make_float4(C[0], C[1], C[2], C[3]);
  *(float4*)&lc[wid][lane * 8 + 4]       = make_float4(C[4], C[5], C[6], C[7]);
  *(float4*)&lc[wid][512 + lane * 8]     = make_float4(C[8], C[9], C[10], C[11]);
  *(float4*)&lc[wid][512 + lane * 8 + 4] = make_float4(C[12], C[13], C[14], C[15]);
  __syncthreads();
  #pragma unroll
  for (int k = 0; k < 2; k++) {
    int col = tid + k * 512;
    float S = 0.f;
    #pragma unroll
    for (int w = 0; w < 8; w++) S += lc[w][col];
    pc[(size_t)blockIdx.x * 1024 + col] = S;
  }
}

__global__ __launch_bounds__(512) void iter32_k(const float* __restrict__ Kb,
                                                const float* __restrict__ Vp,
                                                float* __restrict__ pc) {
  __shared__ float lc[8][1024];
  int tid = threadIdx.x, lane = tid & 63, wid = tid >> 6;
  int row0 = (blockIdx.x * 8 + wid) * 8;
  int b = row0 >> 11;
  const float* vp = Vp + b * TV;
  float vpl[16];
  #pragma unroll
  for (int q = 0; q < 4; q++)
    *(float4*)&vpl[q * 4] = *(const float4*)&vp[q * 256 + lane * 4];
  float C[16];
  #pragma unroll
  for (int i = 0; i < 16; i++) C[i] = 0.f;

  #pragma unroll 2
  for (int r = 0; r < 8; r++) {
    const float* row = Kb + (size_t)(row0 + r) * TV;
    float e[16];
    float s = 0.f;
    #pragma unroll
    for (int q = 0; q < 4; q++) {
      float4 kv = *(const float4*)&row[q * 256 + lane * 4];
      e[q*4+0] = exp2f(kv.x + vpl[q*4+0]);
      e[q*4+1] = exp2f(kv.y + vpl[q*4+1]);
      e[q*4+2] = exp2f(kv.z + vpl[q*4+2]);
      e[q*4+3] = exp2f(kv.w + vpl[q*4+3]);
      s += e[q*4+0] + e[q*4+1] + e[q*4+2] + e[q*4+3];
    }
    s = wave_sum(s);
    float w = 1.0f / s;
    #pragma unroll
    for (int i = 0; i < 16; i++) C[i] = fmaf(e[i], w, C[i]);
  }

  #pragma unroll
  for (int q = 0; q < 4; q++)
    *(float4*)&lc[wid][q * 256 + lane * 4] =
        make_float4(C[q*4+0], C[q*4+1], C[q*4+2], C[q*4+3]);
  __syncthreads();
  #pragma unroll
  for (int k = 0; k < 2; k++) {
    int col = tid + k * 512;
    float S = 0.f;
    #pragma unroll
    for (int w = 0; w < 8; w++) S += lc[w][col];
    pc[(size_t)blockIdx.x * 1024 + col] = S;
  }
}

__global__ void vcomb_k(const float* __restrict__ pc, float* __restrict__ Vp) {
  int i = blockIdx.x * blockDim.x + threadIdx.x;
  int b = i >> 10, j = i & 1023;
  const float* p = pc + (size_t)(b * 32) * 1024 + j;
  float S = 0.f;
  #pragma unroll
  for (int c = 0; c < 32; c++) S += p[c * 1024];
  Vp[i] -= log2f(S);
}

__global__ __launch_bounds__(256) void final16_k(const _Float16* __restrict__ Kh,
                                                 const float* __restrict__ Vp,
                                                 float* __restrict__ out) {
  int gw   = (blockIdx.x * blockDim.x + threadIdx.x) >> 6;
  int lane = threadIdx.x & 63;
  int b = gw >> 11;
  const float* vp = Vp + b * TV + lane * 8;
  float vpl[16];
  *(float4*)&vpl[0]  = *(const float4*)&vp[0];
  *(float4*)&vpl[4]  = *(const float4*)&vp[4];
  *(float4*)&vpl[8]  = *(const float4*)&vp[512];
  *(float4*)&vpl[12] = *(const float4*)&vp[516];
  const _Float16* row = Kh + (size_t)gw * TV + lane * 8;
  half8 h0 = *(const half8*)&row[0];
  half8 h1 = *(const half8*)&row[512];
  float e[16];
  float s = 0.f;
  #pragma unroll
  for (int i = 0; i < 8; i++) { e[i] = exp2f((float)h0[i] + vpl[i]); s += e[i]; }
  #pragma unroll
  for (int i = 0; i < 8; i++) { e[8 + i] = exp2f((float)h1[i] + vpl[8 + i]); s += e[8 + i]; }
  s = wave_sum(s);
  float inv = 1.0f / s;
  float* o = out + (size_t)gw * TV + lane * 8;
  *(float4*)&o[0]   = make_float4(e[0] * inv, e[1] * inv, e[2] * inv, e[3] * inv);
  *(float4*)&o[4]   = make_float4(e[4] * inv, e[5] * inv, e[6] * inv, e[7] * inv);
  *(float4*)&o[512] = make_float4(e[8] * inv, e[9] * inv, e[10] * inv, e[11] * inv);
  *(float4*)&o[516] = make_float4(e[12] * inv, e[13] * inv, e[14] * inv, e[15] * inv);
}

__global__ __launch_bounds__(256) void final32_k(float* __restrict__ Kb,
                                                 const float* __restrict__ Vp) {
  int gw   = (blockIdx.x * blockDim.x + threadIdx.x) >> 6;
  int lane = threadIdx.x & 63;
  int b = gw >> 11;
  const float* vp = Vp + b * TV;
  float* row = Kb + (size_t)gw * TV;
  float e[16];
  float s = 0.f;
  #pragma unroll
  for (int q = 0; q < 4; q++) {
    float4 kv = *(const float4*)&row[q * 256 + lane * 4];
    float4 vv = *(const float4*)&vp[q * 256 + lane * 4];
    e[q*4+0] = exp2f(kv.x + vv.x); e[q*4+1] = exp2f(kv.y + vv.y);
    e[q*4+2] = exp2f(kv.z + vv.z); e[q*4+3] = exp2f(kv.w + vv.w);
    s += e[q*4+0] + e[q*4+1] + e[q*4+2] + e[q*4+3];
  }
  s = wave_sum(s);
  float inv = 1.0f / s;
  #pragma unroll
  for (int q = 0; q < 4; q++)
    *(float4*)&row[q * 256 + lane * 4] =
        make_float4(e[q*4+0] * inv, e[q*4+1] * inv, e[q*4+2] * inv, e[q*4+3] * inv);
}

extern "C" void kernel_launch(void* const* d_in, const int* in_sizes, int n_in,
                              void* d_out, int out_size, void* d_ws, size_t ws_size,
                              hipStream_t stream) {
  const float* audio   = (const float*)d_in[0];
  const float* video   = (const float*)d_in[1];
  const float* quality = (const float*)d_in[2];
  const float* lam_t   = (const float*)d_in[3];
  const float* lam_q   = (const float*)d_in[4];

  float* out = (float*)d_out;
  float* ws  = (float*)d_ws;
  float* inv_na = ws;                         // 32768
  float* inv_nv = ws + 32768;                 // 16384
  float* Vp     = ws + 49152;                 // 16384
  float* pc     = ws + 65536;                 // 524288 (coop: 2 x 256*1024)
  _Float16* Kh  = (_Float16*)(ws + 589824);   // 64 MiB

  size_t need_f16 = 589824ull * 4 + (size_t)B_ * TA * TV * 2;

  norms_k<<<12288, 256, 0, stream>>>(audio, video, inv_na, inv_nv);
  vinit_k<<<64, 256, 0, stream>>>(quality, lam_q, Vp);

  if (ws_size >= need_f16) {
    cost_k<true><<<dim3(16, 8, 16), 256, 0, stream>>>(audio, video, inv_na, inv_nv,
                                                      lam_t, nullptr, Kh);
    const _Float16* Khc = Kh;
    const float* Vpc = Vp;
    void* args[] = { (void*)&Khc, (void*)&Vpc, (void*)&pc, (void*)&out };
    hipError_t err = hipLaunchCooperativeKernel((const void*)coop_k, dim3(256),
                                                dim3(1024), args, 0, stream);
    if (err != hipSuccess) {
      for (int it = 0; it < NIT; it++) {
        iter16_k<<<512, 512, 0, stream>>>(Kh, Vp, pc);
        vcomb_k<<<64, 256, 0, stream>>>(pc, Vp);
      }
      final16_k<<<8192, 256, 0, stream>>>(Kh, Vp, out);
    }
  } else {
    float* Kb = out;
    cost_k<false><<<dim3(16, 8, 16), 256, 0, stream>>>(audio, video, inv_na, inv_nv,
                                                       lam_t, Kb, nullptr);
    for (int it = 0; it < NIT; it++) {
      iter32_k<<<512, 512, 0, stream>>>(Kb, Vp, pc);
      vcomb_k<<<64, 256, 0, stream>>>(pc, Vp);
    }
    final32_k<<<8192, 256, 0, stream>>>(Kb, Vp);
  }
}

// Round 7
// 503.406 us; speedup vs baseline: 6.5395x; 3.9846x over previous
//
#include <hip/hip_runtime.h>
#include <hip/hip_fp16.h>

#define B_  16
#define TA  2048
#define TV  1024
#define DD  512
#define NIT 20

static constexpr float EPSI  = 0.15f;
static constexpr float LOG2E = 1.4426950408889634f;

using f32x4 = __attribute__((ext_vector_type(4))) float;
using half8 = __attribute__((ext_vector_type(8))) _Float16;
using half4 = __attribute__((ext_vector_type(4))) _Float16;

__device__ inline float wave_sum(float x) {
  #pragma unroll
  for (int m = 32; m; m >>= 1) x += __shfl_xor(x, m, 64);
  return x;
}

// bank-spread swizzle for stride-64B f32 vector access
__device__ inline int swz(int c) { return c ^ (((c >> 5) & 7) << 2); }

// ---------------- norms: inv L2 norm per row (audio rows then video rows) ---
__global__ __launch_bounds__(256) void norms_k(const float* __restrict__ audio,
                                               const float* __restrict__ video,
                                               float* __restrict__ inv_na,
                                               float* __restrict__ inv_nv) {
  int wid  = (blockIdx.x * blockDim.x + threadIdx.x) >> 6;
  int lane = threadIdx.x & 63;
  const float* src;
  float* dst;
  if (wid < B_ * TA) { src = audio + (size_t)wid * DD; dst = inv_na + wid; }
  else               { src = video + (size_t)(wid - B_ * TA) * DD; dst = inv_nv + (wid - B_ * TA); }
  const float4* s4 = (const float4*)src;
  float ss = 0.f;
  #pragma unroll
  for (int i = 0; i < 2; i++) {
    float4 v = s4[lane + i * 64];
    ss += v.x * v.x + v.y * v.y + v.z * v.z + v.w * v.w;
  }
  ss = wave_sum(ss);
  if (lane == 0) *dst = 1.0f / fmaxf(sqrtf(ss), 1e-12f);
}

// ---------------- v' init: v' = -c1 * lam_q * (1 - quality) ----------------
__global__ void vinit_k(const float* __restrict__ quality,
                        const float* __restrict__ lam_q,
                        float* __restrict__ Vp) {
  int i = blockIdx.x * blockDim.x + threadIdx.x;  // 0..B_*TV-1
  float c1 = LOG2E / EPSI;
  Vp[i] = -c1 * (*lam_q) * (1.0f - quality[i]);
}

// ---------------- cost GEMM: Ksmall2 = c1*(sim - 1 - lt*timedist) ----------
#define BM 128
#define BN 128
#define BK 64
#define LDH 72

template<bool F16>
__global__ __launch_bounds__(256) void cost_k(const float* __restrict__ audio,
                                              const float* __restrict__ video,
                                              const float* __restrict__ inv_na,
                                              const float* __restrict__ inv_nv,
                                              const float* __restrict__ lam_t,
                                              float* __restrict__ Kb,
                                              _Float16* __restrict__ Kh) {
  __shared__ _Float16 As[BM * LDH];
  __shared__ _Float16 Bs[BN * LDH];
  int b  = blockIdx.z;
  int a0 = blockIdx.x * BM;
  int j0 = blockIdx.y * BN;
  int tid  = threadIdx.x;
  int lane = tid & 63;
  int wid  = tid >> 6;
  int wm = wid >> 1, wn = wid & 1;

  const float* Ab = audio + (size_t)b * TA * DD;
  const float* Vb = video + (size_t)b * TV * DD;

  f32x4 acc[4][4];
  #pragma unroll
  for (int i = 0; i < 4; i++)
    #pragma unroll
    for (int j = 0; j < 4; j++)
      #pragma unroll
      for (int r = 0; r < 4; r++) acc[i][j][r] = 0.f;

  int frow = tid >> 4;
  int fcol = (tid & 15) * 4;
  int l16 = lane & 15, lq = lane >> 4;

  for (int kb = 0; kb < DD; kb += BK) {
    __syncthreads();
    #pragma unroll
    for (int s = 0; s < 8; s++) {
      int r = frow + s * 16;
      float4 v = *(const float4*)&Ab[(size_t)(a0 + r) * DD + kb + fcol];
      float sc = inv_na[b * TA + a0 + r];
      half4 h = { (_Float16)(v.x * sc), (_Float16)(v.y * sc),
                  (_Float16)(v.z * sc), (_Float16)(v.w * sc) };
      *(half4*)&As[r * LDH + fcol] = h;
    }
    #pragma unroll
    for (int s = 0; s < 8; s++) {
      int r = frow + s * 16;
      float4 v = *(const float4*)&Vb[(size_t)(j0 + r) * DD + kb + fcol];
      float sc = inv_nv[b * TV + j0 + r];
      half4 h = { (_Float16)(v.x * sc), (_Float16)(v.y * sc),
                  (_Float16)(v.z * sc), (_Float16)(v.w * sc) };
      *(half4*)&Bs[r * LDH + fcol] = h;
    }
    __syncthreads();
    #pragma unroll
    for (int ks = 0; ks < 2; ks++) {
      half8 af[4], bf[4];
      #pragma unroll
      for (int mf = 0; mf < 4; mf++)
        af[mf] = *(const half8*)&As[(wm * 64 + mf * 16 + l16) * LDH + ks * 32 + lq * 8];
      #pragma unroll
      for (int nf = 0; nf < 4; nf++)
        bf[nf] = *(const half8*)&Bs[(wn * 64 + nf * 16 + l16) * LDH + ks * 32 + lq * 8];
      #pragma unroll
      for (int mf = 0; mf < 4; mf++)
        #pragma unroll
        for (int nf = 0; nf < 4; nf++)
          acc[mf][nf] = __builtin_amdgcn_mfma_f32_16x16x32_f16(af[mf], bf[nf], acc[mf][nf], 0, 0, 0);
    }
  }

  float lt = *lam_t;
  float c1 = LOG2E / EPSI;
  #pragma unroll
  for (int mf = 0; mf < 4; mf++)
    #pragma unroll
    for (int nf = 0; nf < 4; nf++)
      #pragma unroll
      for (int r = 0; r < 4; r++) {
        int a = a0 + wm * 64 + mf * 16 + lq * 4 + r;
        int j = j0 + wn * 64 + nf * 16 + l16;
        float sim = acc[mf][nf][r];
        float td = fabsf((float)a * (1.0f / TA) - (float)j * (1.0f / TV));
        float val = c1 * (sim - 1.0f - lt * td);
        size_t o = ((size_t)b * TA + a) * TV + j;
        if constexpr (F16) Kh[o] = (_Float16)val;
        else               Kb[o] = val;
      }
}

// ---------------- persistent Sinkhorn, K in VGPRs, INLINE per-batch sync ---
// 256 blocks x 1024 thr (16 waves), waves_per_eu(4,4) pins 1 block/CU and a
// 128-VGPR budget (K = 64 VGPR + ~55 working). No grid.sync() call -> no
// caller-save spill. Blocks of one batch (16) sync via device-scope counter.
__global__ __launch_bounds__(1024) __attribute__((amdgpu_waves_per_eu(4, 4)))
void coop2_k(const _Float16* __restrict__ Kh,
             const float* __restrict__ Vp0,
             float* __restrict__ pc,
             int* __restrict__ cnt,
             float* __restrict__ out) {
  __shared__ float lc[16][1024];
  __shared__ float vbuf[1024];
  const int tid  = threadIdx.x, lane = tid & 63, wid = tid >> 6;  // wid 0..15
  const int bid  = blockIdx.x;
  const int row0 = bid * 128 + wid * 8;    // wave's first global row
  const int b    = bid >> 4;               // batch (16 blocks per batch)
  const int col0 = lane * 16;

  // block-local copy of this batch's Vp (swizzled storage)
  if (tid < 256) {
    f32x4 v = *(const f32x4*)&Vp0[b * TV + tid * 4];
    *(f32x4*)&vbuf[swz(tid * 4)] = v;
  }

  // stage this wave's K rows into registers (8 rows x 16 cols f16 = 64 VGPR)
  half8 h[8][2];
  #pragma unroll
  for (int r = 0; r < 8; r++) {
    const _Float16* rp = Kh + (size_t)(row0 + r) * TV + col0;
    h[r][0] = *(const half8*)&rp[0];
    h[r][1] = *(const half8*)&rp[8];
  }
  __syncthreads();

  float vpl[16];
  #pragma unroll
  for (int q = 0; q < 4; q++)
    *(f32x4*)&vpl[q * 4] = *(const f32x4*)&vbuf[swz(col0 + q * 4)];

  for (int it = 0; it < NIT; it++) {
    float* pcb = pc + (size_t)(it & 1) * (256 * 1024);
    float C[16];
    #pragma unroll
    for (int i = 0; i < 16; i++) C[i] = 0.f;

    #pragma unroll
    for (int r = 0; r < 8; r++) {
      float e[16];
      float s = 0.f;
      #pragma unroll
      for (int i = 0; i < 16; i++) {
        e[i] = exp2f((float)h[r][i >> 3][i & 7] + vpl[i]);
        s += e[i];
      }
      s = wave_sum(s);
      float w = 1.0f / s;
      #pragma unroll
      for (int i = 0; i < 16; i++) C[i] = fmaf(e[i], w, C[i]);
    }

    // merge 16 waves' column partials in LDS (swizzled)
    #pragma unroll
    for (int q = 0; q < 4; q++)
      *(f32x4*)&lc[wid][swz(col0 + q * 4)] = *(f32x4*)&C[q * 4];
    __syncthreads();
    {
      int col = tid;               // 1024 threads, 1024 cols
      int sc_ = swz(col);
      float S = 0.f;
      #pragma unroll
      for (int w = 0; w < 16; w++) S += lc[w][sc_];
      pcb[(size_t)bid * 1024 + col] = S;
    }

    // ---- inline per-batch sync (16 blocks), fully inlined: no spills ----
    __syncthreads();                       // all pcb writes of this block issued
    if (tid == 0) {
      __threadfence();                     // agent-scope release (L2 writeback)
      __hip_atomic_fetch_add(&cnt[it * 16 + b], 1, __ATOMIC_RELEASE,
                             __HIP_MEMORY_SCOPE_AGENT);
      int v;
      do {
        v = __hip_atomic_load(&cnt[it * 16 + b], __ATOMIC_ACQUIRE,
                              __HIP_MEMORY_SCOPE_AGENT);
        if (v < 16) __builtin_amdgcn_s_sleep(1);
      } while (v < 16);
    }
    __syncthreads();

    // every block redundantly reduces its batch's 16 partials -> local Vp
    {
      int col = tid;
      const float* p = pcb + (size_t)(b * 16) * 1024 + col;
      float S = 0.f;
      #pragma unroll
      for (int c = 0; c < 16; c++) S += p[c * 1024];
      vbuf[swz(col)] -= log2f(S);
    }
    __syncthreads();
    #pragma unroll
    for (int q = 0; q < 4; q++)
      *(f32x4*)&vpl[q * 4] = *(const f32x4*)&vbuf[swz(col0 + q * 4)];
  }

  // final: transport = row-softmax(K + Vp_final), K still in registers
  #pragma unroll 2
  for (int r = 0; r < 8; r++) {
    float e[16], s = 0.f;
    #pragma unroll
    for (int i = 0; i < 16; i++) {
      e[i] = exp2f((float)h[r][i >> 3][i & 7] + vpl[i]);
      s += e[i];
    }
    s = wave_sum(s);
    float w = 1.0f / s;
    float* o = out + (size_t)(row0 + r) * TV + col0;
    #pragma unroll
    for (int q = 0; q < 4; q++) {
      f32x4 ov = { e[q*4+0] * w, e[q*4+1] * w, e[q*4+2] * w, e[q*4+3] * w };
      *(f32x4*)&o[q * 4] = ov;
    }
  }
}

// ---------------- fallback loop kernels (round-3 path) ---------------------
__global__ __launch_bounds__(512) void iter16_k(const _Float16* __restrict__ Kh,
                                                const float* __restrict__ Vp,
                                                float* __restrict__ pc) {
  __shared__ float lc[8][1024];
  int tid = threadIdx.x, lane = tid & 63, wid = tid >> 6;
  int row0 = (blockIdx.x * 8 + wid) * 8;
  int b = row0 >> 11;
  const float* vp = Vp + b * TV + lane * 8;
  float vpl[16];
  *(float4*)&vpl[0]  = *(const float4*)&vp[0];
  *(float4*)&vpl[4]  = *(const float4*)&vp[4];
  *(float4*)&vpl[8]  = *(const float4*)&vp[512];
  *(float4*)&vpl[12] = *(const float4*)&vp[516];
  float C[16];
  #pragma unroll
  for (int i = 0; i < 16; i++) C[i] = 0.f;

  #pragma unroll 2
  for (int r = 0; r < 8; r++) {
    const _Float16* row = Kh + (size_t)(row0 + r) * TV + lane * 8;
    half8 h0 = *(const half8*)&row[0];
    half8 h1 = *(const half8*)&row[512];
    float e[16];
    float s = 0.f;
    #pragma unroll
    for (int i = 0; i < 8; i++) { e[i] = exp2f((float)h0[i] + vpl[i]); s += e[i]; }
    #pragma unroll
    for (int i = 0; i < 8; i++) { e[8 + i] = exp2f((float)h1[i] + vpl[8 + i]); s += e[8 + i]; }
    s = wave_sum(s);
    float w = 1.0f / s;
    #pragma unroll
    for (int i = 0; i < 16; i++) C[i] = fmaf(e[i], w, C[i]);
  }

  *(float4*)&lc[wid][lane * 8]           = make_float4(C[0], C[1], C[2], C[3]);
  *(float4*)&lc[wid][lane * 8 + 4]       = make_float4(C[4], C[5], C[6], C[7]);
  *(float4*)&lc[wid][512 + lane * 8]     = make_float4(C[8], C[9], C[10], C[11]);
  *(float4*)&lc[wid][512 + lane * 8 + 4] = make_float4(C[12], C[13], C[14], C[15]);
  __syncthreads();
  #pragma unroll
  for (int k = 0; k < 2; k++) {
    int col = tid + k * 512;
    float S = 0.f;
    #pragma unroll
    for (int w = 0; w < 8; w++) S += lc[w][col];
    pc[(size_t)blockIdx.x * 1024 + col] = S;
  }
}

__global__ __launch_bounds__(512) void iter32_k(const float* __restrict__ Kb,
                                                const float* __restrict__ Vp,
                                                float* __restrict__ pc) {
  __shared__ float lc[8][1024];
  int tid = threadIdx.x, lane = tid & 63, wid = tid >> 6;
  int row0 = (blockIdx.x * 8 + wid) * 8;
  int b = row0 >> 11;
  const float* vp = Vp + b * TV;
  float vpl[16];
  #pragma unroll
  for (int q = 0; q < 4; q++)
    *(float4*)&vpl[q * 4] = *(const float4*)&vp[q * 256 + lane * 4];
  float C[16];
  #pragma unroll
  for (int i = 0; i < 16; i++) C[i] = 0.f;

  #pragma unroll 2
  for (int r = 0; r < 8; r++) {
    const float* row = Kb + (size_t)(row0 + r) * TV;
    float e[16];
    float s = 0.f;
    #pragma unroll
    for (int q = 0; q < 4; q++) {
      float4 kv = *(const float4*)&row[q * 256 + lane * 4];
      e[q*4+0] = exp2f(kv.x + vpl[q*4+0]);
      e[q*4+1] = exp2f(kv.y + vpl[q*4+1]);
      e[q*4+2] = exp2f(kv.z + vpl[q*4+2]);
      e[q*4+3] = exp2f(kv.w + vpl[q*4+3]);
      s += e[q*4+0] + e[q*4+1] + e[q*4+2] + e[q*4+3];
    }
    s = wave_sum(s);
    float w = 1.0f / s;
    #pragma unroll
    for (int i = 0; i < 16; i++) C[i] = fmaf(e[i], w, C[i]);
  }

  #pragma unroll
  for (int q = 0; q < 4; q++)
    *(float4*)&lc[wid][q * 256 + lane * 4] =
        make_float4(C[q*4+0], C[q*4+1], C[q*4+2], C[q*4+3]);
  __syncthreads();
  #pragma unroll
  for (int k = 0; k < 2; k++) {
    int col = tid + k * 512;
    float S = 0.f;
    #pragma unroll
    for (int w = 0; w < 8; w++) S += lc[w][col];
    pc[(size_t)blockIdx.x * 1024 + col] = S;
  }
}

__global__ void vcomb_k(const float* __restrict__ pc, float* __restrict__ Vp) {
  int i = blockIdx.x * blockDim.x + threadIdx.x;
  int b = i >> 10, j = i & 1023;
  const float* p = pc + (size_t)(b * 32) * 1024 + j;
  float S = 0.f;
  #pragma unroll
  for (int c = 0; c < 32; c++) S += p[c * 1024];
  Vp[i] -= log2f(S);
}

__global__ __launch_bounds__(256) void final16_k(const _Float16* __restrict__ Kh,
                                                 const float* __restrict__ Vp,
                                                 float* __restrict__ out) {
  int gw   = (blockIdx.x * blockDim.x + threadIdx.x) >> 6;
  int lane = threadIdx.x & 63;
  int b = gw >> 11;
  const float* vp = Vp + b * TV + lane * 8;
  float vpl[16];
  *(float4*)&vpl[0]  = *(const float4*)&vp[0];
  *(float4*)&vpl[4]  = *(const float4*)&vp[4];
  *(float4*)&vpl[8]  = *(const float4*)&vp[512];
  *(float4*)&vpl[12] = *(const float4*)&vp[516];
  const _Float16* row = Kh + (size_t)gw * TV + lane * 8;
  half8 h0 = *(const half8*)&row[0];
  half8 h1 = *(const half8*)&row[512];
  float e[16];
  float s = 0.f;
  #pragma unroll
  for (int i = 0; i < 8; i++) { e[i] = exp2f((float)h0[i] + vpl[i]); s += e[i]; }
  #pragma unroll
  for (int i = 0; i < 8; i++) { e[8 + i] = exp2f((float)h1[i] + vpl[8 + i]); s += e[8 + i]; }
  s = wave_sum(s);
  float inv = 1.0f / s;
  float* o = out + (size_t)gw * TV + lane * 8;
  *(float4*)&o[0]   = make_float4(e[0] * inv, e[1] * inv, e[2] * inv, e[3] * inv);
  *(float4*)&o[4]   = make_float4(e[4] * inv, e[5] * inv, e[6] * inv, e[7] * inv);
  *(float4*)&o[512] = make_float4(e[8] * inv, e[9] * inv, e[10] * inv, e[11] * inv);
  *(float4*)&o[516] = make_float4(e[12] * inv, e[13] * inv, e[14] * inv, e[15] * inv);
}

__global__ __launch_bounds__(256) void final32_k(float* __restrict__ Kb,
                                                 const float* __restrict__ Vp) {
  int gw   = (blockIdx.x * blockDim.x + threadIdx.x) >> 6;
  int lane = threadIdx.x & 63;
  int b = gw >> 11;
  const float* vp = Vp + b * TV;
  float* row = Kb + (size_t)gw * TV;
  float e[16];
  float s = 0.f;
  #pragma unroll
  for (int q = 0; q < 4; q++) {
    float4 kv = *(const float4*)&row[q * 256 + lane * 4];
    float4 vv = *(const float4*)&vp[q * 256 + lane * 4];
    e[q*4+0] = exp2f(kv.x + vv.x); e[q*4+1] = exp2f(kv.y + vv.y);
    e[q*4+2] = exp2f(kv.z + vv.z); e[q*4+3] = exp2f(kv.w + vv.w);
    s += e[q*4+0] + e[q*4+1] + e[q*4+2] + e[q*4+3];
  }
  s = wave_sum(s);
  float inv = 1.0f / s;
  #pragma unroll
  for (int q = 0; q < 4; q++)
    *(float4*)&row[q * 256 + lane * 4] =
        make_float4(e[q*4+0] * inv, e[q*4+1] * inv, e[q*4+2] * inv, e[q*4+3] * inv);
}

extern "C" void kernel_launch(void* const* d_in, const int* in_sizes, int n_in,
                              void* d_out, int out_size, void* d_ws, size_t ws_size,
                              hipStream_t stream) {
  const float* audio   = (const float*)d_in[0];
  const float* video   = (const float*)d_in[1];
  const float* quality = (const float*)d_in[2];
  const float* lam_t   = (const float*)d_in[3];
  const float* lam_q   = (const float*)d_in[4];

  float* out = (float*)d_out;
  float* ws  = (float*)d_ws;
  float* inv_na = ws;                         // 32768
  float* inv_nv = ws + 32768;                 // 16384
  float* Vp     = ws + 49152;                 // 16384
  float* pc     = ws + 65536;                 // 524288 (coop: 2 x 256*1024)
  _Float16* Kh  = (_Float16*)(ws + 589824);   // 64 MiB (8388608 floats)
  int*   cnt    = (int*)(ws + 589824 + 8388608);  // NIT*16 ints

  size_t need_f16 = (589824ull + 8388608ull + NIT * 16) * 4;

  norms_k<<<12288, 256, 0, stream>>>(audio, video, inv_na, inv_nv);
  vinit_k<<<64, 256, 0, stream>>>(quality, lam_q, Vp);

  if (ws_size >= need_f16) {
    cost_k<true><<<dim3(16, 8, 16), 256, 0, stream>>>(audio, video, inv_na, inv_nv,
                                                      lam_t, nullptr, Kh);
    // guard: only take the persistent path if it compiled spill-free
    hipFuncAttributes attr{};
    bool coop_ok = (hipFuncGetAttributes(&attr, (const void*)coop2_k) == hipSuccess)
                   && attr.localSizeBytes == 0;
    if (coop_ok) {
      hipMemsetAsync(cnt, 0, NIT * 16 * sizeof(int), stream);
      const _Float16* Khc = Kh;
      const float* Vpc = Vp;
      void* args[] = { (void*)&Khc, (void*)&Vpc, (void*)&pc, (void*)&cnt, (void*)&out };
      hipError_t err = hipLaunchCooperativeKernel((const void*)coop2_k, dim3(256),
                                                  dim3(1024), args, 0, stream);
      if (err == hipSuccess) return;
    }
    for (int it = 0; it < NIT; it++) {
      iter16_k<<<512, 512, 0, stream>>>(Kh, Vp, pc);
      vcomb_k<<<64, 256, 0, stream>>>(pc, Vp);
    }
    final16_k<<<8192, 256, 0, stream>>>(Kh, Vp, out);
  } else {
    float* Kb = out;
    cost_k<false><<<dim3(16, 8, 16), 256, 0, stream>>>(audio, video, inv_na, inv_nv,
                                                       lam_t, Kb, nullptr);
    for (int it = 0; it < NIT; it++) {
      iter32_k<<<512, 512, 0, stream>>>(Kb, Vp, pc);
      vcomb_k<<<64, 256, 0, stream>>>(pc, Vp);
    }
    final32_k<<<8192, 256, 0, stream>>>(Kb, Vp);
  }
}